// Round 13
// baseline (241.656 us; speedup 1.0000x reference)
//
#include <hip/hip_runtime.h>
#include <hip/hip_bf16.h>
#include <hip/hip_fp16.h>

#define N_NODES  100000
#define N_GRAPHS 512
#define IN_CH    128
#define HID      32
#define OUT_CH   10
#define N_EDGES  3200000
#define SPLIT    50000                       // src-half threshold (L2 tiling)

#define SZC   256                            // nodes per bucket
#define NBC   ((N_NODES + SZC - 1) / SZC)    // 391
#define CAPC  9216                           // mean 8192, +11 sigma
#define RND   8192                           // edges per binning round
#define BKT   1024                           // threads per bucket_k block
#define EPT   8                              // edges per thread per round
#define NRND  ((N_EDGES + RND - 1) / RND)    // 391

typedef _Float16 half8 __attribute__((ext_vector_type(8)));
typedef float    f32x4 __attribute__((ext_vector_type(4)));

// ---- int32/int64 index loader (low word of little-endian int64) ----
__device__ __forceinline__ int load_idx(const int* __restrict__ p, long long pos, int is64) {
  return is64 ? p[2 * pos] : p[(int)pos];
}

// unpack 8 consecutive halfs (loaded as float4) and accumulate into a[8]
__device__ __forceinline__ void h8_acc(float4 raw, float* a) {
  const __half2* ph = (const __half2*)&raw;
#pragma unroll
  for (int q = 0; q < 4; q++) {
    float2 f = __half22float2(ph[q]);
    a[2 * q]     += f.x;
    a[2 * q + 1] += f.y;
  }
}

// Detect whether index buffers are int64. block 0 -> ei flag, block 1 -> batch.
__global__ void detect_i64(const int* __restrict__ ei, const int* __restrict__ batch,
                           int* __restrict__ flag) {
  __shared__ int any_nz;
  const int* buf = (blockIdx.x == 0) ? ei : batch;
  if (threadIdx.x == 0) any_nz = 0;
  __syncthreads();
  for (int i = threadIdx.x; i < 4096; i += 256) {
    if (buf[2 * i + 1] != 0) any_nz = 1;
  }
  __syncthreads();
  if (threadIdx.x == 0) flag[blockIdx.x] = any_nz ? 0 : 1;
}

// ---- pack W[K][32] f32 into MFMA B-fragment order, fp16; also zero gcur
//      (replaces hipMemsetAsync -> no rocclr fill dispatch in the graph) ----
__global__ void pack_w(const float* __restrict__ W1, const float* __restrict__ W2,
                       const float* __restrict__ W3, __half* __restrict__ P1,
                       __half* __restrict__ P2, __half* __restrict__ P3,
                       int* __restrict__ gcur) {
  int t = threadIdx.x;
  for (int i = t; i < NBC; i += 256) gcur[i] = 0;
  for (int idx = t; idx < 4 * 2 * 64 * 8; idx += 256) {   // W1: K=128 -> 4 k-steps
    int j = idx & 7, l = (idx >> 3) & 63, ct = (idx >> 9) & 1, s = idx >> 10;
    int k = s * 32 + (l >> 4) * 8 + j, c = ct * 16 + (l & 15);
    P1[idx] = __float2half(W1[k * 32 + c]);
  }
  for (int idx = t; idx < 2 * 64 * 8; idx += 256) {       // W2,W3: K=32 -> 1 k-step
    int j = idx & 7, l = (idx >> 3) & 63, ct = (idx >> 9) & 1;
    int k = (l >> 4) * 8 + j, c = ct * 16 + (l & 15);
    P2[idx] = __float2half(W2[k * 32 + c]);
    P3[idx] = __float2half(W3[k * 32 + c]);
  }
}

// ---- pass 1: round-based binning. 391 blocks x 1024 threads ----
__global__ void bucket_k(const int* __restrict__ ei, const int* __restrict__ flag,
                         int* __restrict__ gcur, int* __restrict__ bstore) {
  __shared__ int hist[NBC];
  __shared__ int base[NBC];
  int is64 = flag[0];
  int t = threadIdx.x;
  int rd = blockIdx.x;
  for (int i = t; i < NBC; i += BKT) hist[i] = 0;
  __syncthreads();
  long long e0 = (long long)rd * RND;
  int   pk[EPT];
  short cb[EPT];
#pragma unroll
  for (int k = 0; k < EPT; k++) {
    long long e = e0 + k * BKT + t;
    if (e < N_EDGES) {
      int s = load_idx(ei, e, is64);
      int d = load_idx(ei, N_EDGES + e, is64);
      pk[k] = (s << 8) | (d & 255);
      cb[k] = (short)(d >> 8);
      atomicAdd(&hist[d >> 8], 1);
    } else {
      cb[k] = -1;
    }
  }
  __syncthreads();
  for (int c = t; c < NBC; c += BKT) {
    int h = hist[c];
    if (h > 0) base[c] = atomicAdd(&gcur[c], h);
  }
  __syncthreads();
#pragma unroll
  for (int k = 0; k < EPT; k++) {
    if (cb[k] >= 0) {
      int c = cb[k];
      int pos = atomicAdd(&base[c], 1);          // LDS cursor from global base
      if (pos < CAPC) bstore[(size_t)c * CAPC + pos] = pk[k];
    }
  }
}

// ---- exclusive scan of clamped coarse-bucket counts -> global bases ----
__global__ void bscan_k(const int* __restrict__ gcur, int* __restrict__ bbase) {
  __shared__ int part[256];
  int t = threadIdx.x;
  const int CHUNK = (NBC + 255) / 256;  // 2
  int v[CHUNK];
  int s = 0;
  int base = t * CHUNK;
  for (int k = 0; k < CHUNK; k++) {
    int i = base + k;
    v[k] = (i < NBC) ? min(gcur[i], CAPC) : 0;
    s += v[k];
  }
  part[t] = s;
  __syncthreads();
  if (t == 0) {
    int run = 0;
    for (int i = 0; i < 256; i++) { int x = part[i]; part[i] = run; run += x; }
  }
  __syncthreads();
  int run = part[t];
  for (int k = 0; k < CHUNK; k++) {
    int i = base + k;
    if (i < NBC) bbase[i] = run;
    run += v[k];
  }
}

// ---- per-bucket LDS counting sort with composite key (dst_local, src_half):
//      csr per node = [src<SPLIT edges][src>=SPLIT edges]; emits deg_lo. ----
__global__ void build_csr(const int* __restrict__ bstore, const int* __restrict__ gcur,
                          const int* __restrict__ bbase, int* __restrict__ csr,
                          int* __restrict__ row_ptr, int* __restrict__ deg,
                          int* __restrict__ deg_lo, float* __restrict__ dinv) {
  __shared__ int hist[2 * SZC];
  __shared__ int sc[SZC];
  __shared__ int cur[2 * SZC];
  int b = blockIdx.x, t = threadIdx.x;
  hist[t] = 0;
  hist[t + 256] = 0;
  __syncthreads();
  int cnt = min(gcur[b], CAPC);
  const int* eb = bstore + (size_t)b * CAPC;
  for (int i = t; i < cnt; i += 256) {
    int pk = eb[i];
    int key = ((pk & 255) << 1) | ((pk >> 8) >= SPLIT ? 1 : 0);
    atomicAdd(&hist[key], 1);
  }
  __syncthreads();
  int lo = hist[2 * t], hi = hist[2 * t + 1];
  int own = lo + hi;
  sc[t] = own;
  __syncthreads();
  for (int off = 1; off < SZC; off <<= 1) {
    int u = (t >= off) ? sc[t - off] : 0;
    __syncthreads();
    sc[t] += u;
    __syncthreads();
  }
  int excl = sc[t] - own;
  int gbase = bbase[b];
  int node = b * SZC + t;
  if (node < N_NODES) {
    row_ptr[node] = gbase + excl;
    deg[node]     = own;
    deg_lo[node]  = lo;
    dinv[node]    = rsqrtf((float)(own + 1));  // +1 self-loop
  }
  cur[2 * t]     = excl;
  cur[2 * t + 1] = excl + lo;
  __syncthreads();
  for (int i = t; i < cnt; i += 256) {
    int pk = eb[i];                              // L2-hot (same block re-read)
    int key = ((pk & 255) << 1) | ((pk >> 8) >= SPLIT ? 1 : 0);
    int pos = atomicAdd(&cur[key], 1);
    csr[gbase + pos] = pk >> 8;
  }
}

// ---- MFMA GEMM: G = fp16( (X @ W) * dinv[row] ), no LDS, no barriers ----
template <int K>
__global__ void gemm_mfma(const float* __restrict__ X, const __half* __restrict__ P,
                          const float* __restrict__ dinv, __half* __restrict__ G) {
  int wid  = threadIdx.x >> 6;
  int lane = threadIdx.x & 63;
  int row0 = (blockIdx.x * 4 + wid) * 16;
  if (row0 >= N_NODES) return;
  int r  = lane & 15;    // A row within tile
  int ko = lane >> 4;    // k-octet selector
  f32x4 acc0 = {0.f, 0.f, 0.f, 0.f};
  f32x4 acc1 = {0.f, 0.f, 0.f, 0.f};
  const float* xrow = X + (size_t)(row0 + r) * K + ko * 8;
#pragma unroll
  for (int s = 0; s < K / 32; s++) {
    float4 xa = *(const float4*)(xrow + s * 32);
    float4 xb = *(const float4*)(xrow + s * 32 + 4);
    half8 a;
    a[0] = (_Float16)xa.x; a[1] = (_Float16)xa.y;
    a[2] = (_Float16)xa.z; a[3] = (_Float16)xa.w;
    a[4] = (_Float16)xb.x; a[5] = (_Float16)xb.y;
    a[6] = (_Float16)xb.z; a[7] = (_Float16)xb.w;
    half8 b0 = *(const half8*)(P + ((size_t)(s * 2 + 0) * 64 + lane) * 8);
    half8 b1 = *(const half8*)(P + ((size_t)(s * 2 + 1) * 64 + lane) * 8);
    acc0 = __builtin_amdgcn_mfma_f32_16x16x32_f16(a, b0, acc0, 0, 0, 0);
    acc1 = __builtin_amdgcn_mfma_f32_16x16x32_f16(a, b1, acc1, 0, 0, 0);
  }
  int col   = lane & 15;
  int rbase = row0 + (lane >> 4) * 4;
#pragma unroll
  for (int i = 0; i < 4; i++) {
    float dn = dinv[rbase + i];
    G[(size_t)(rbase + i) * 32 + col]      = __float2half(acc0[i] * dn);
    G[(size_t)(rbase + i) * 32 + 16 + col] = __float2half(acc1[i] * dn);
  }
}

// ---- L2-tiled pull aggregation, two passes over src-halves.
//      PASS 0: gather only src<SPLIT (low 3.2MB of g — fits every XCD L2),
//              write f32 partial. PASS 1: gather src>=SPLIT, add partial,
//              self-loop, dinv/bias/relu, store. Whole GPU works one half
//              at a time => gathers are L2-resident. ----
template <int PASS>
__global__ void agg_pull(const __half* __restrict__ g, const int* __restrict__ csr,
                         const int* __restrict__ row_ptr, const int* __restrict__ deg,
                         const int* __restrict__ deg_lo, const float* __restrict__ dinv,
                         const float* __restrict__ bias, float* __restrict__ partial,
                         float* __restrict__ out, int do_relu) {
  int node = blockIdx.x * 32 + (threadIdx.x >> 3);
  if (node >= N_NODES) return;
  int half = (threadIdx.x >> 2) & 1;   // which half of this range
  int j    = threadIdx.x & 3;          // feature octet: halfs [j*8, j*8+8)
  const __half* gj = g + j * 8;
  int start = row_ptr[node];
  int dl    = deg_lo[node];
  int base, n;
  if (PASS == 0) { base = start;      n = dl; }
  else           { base = start + dl; n = deg[node] - dl; }
  float a0[8] = {0.f, 0.f, 0.f, 0.f, 0.f, 0.f, 0.f, 0.f};
  float a1[8] = {0.f, 0.f, 0.f, 0.f, 0.f, 0.f, 0.f, 0.f};
  float a2[8] = {0.f, 0.f, 0.f, 0.f, 0.f, 0.f, 0.f, 0.f};
  float a3[8] = {0.f, 0.f, 0.f, 0.f, 0.f, 0.f, 0.f, 0.f};
  int i = half;
  for (; i + 6 < n; i += 8) {         // stride-2 within half, unroll 4
    int s0 = csr[base + i];
    int s1 = csr[base + i + 2];
    int s2 = csr[base + i + 4];
    int s3 = csr[base + i + 6];
    float4 r0 = *(const float4*)(gj + (size_t)s0 * HID);
    float4 r1 = *(const float4*)(gj + (size_t)s1 * HID);
    float4 r2 = *(const float4*)(gj + (size_t)s2 * HID);
    float4 r3 = *(const float4*)(gj + (size_t)s3 * HID);
    h8_acc(r0, a0);
    h8_acc(r1, a1);
    h8_acc(r2, a2);
    h8_acc(r3, a3);
  }
  for (; i < n; i += 2) {
    int s0 = csr[base + i];
    h8_acc(*(const float4*)(gj + (size_t)s0 * HID), a0);
  }
#pragma unroll
  for (int k = 0; k < 8; k++) a0[k] += a1[k] + a2[k] + a3[k];
  // combine the two half-streams (lanes differ in bit 2)
#pragma unroll
  for (int k = 0; k < 8; k++) a0[k] += __shfl_xor(a0[k], 4, 64);
  if (half == 0) {
    if (PASS == 0) {
      *(float4*)(partial + (size_t)node * HID + j * 8)     = make_float4(a0[0], a0[1], a0[2], a0[3]);
      *(float4*)(partial + (size_t)node * HID + j * 8 + 4) = make_float4(a0[4], a0[5], a0[6], a0[7]);
    } else {
      float4 p0 = *(const float4*)(partial + (size_t)node * HID + j * 8);
      float4 p1 = *(const float4*)(partial + (size_t)node * HID + j * 8 + 4);
      float pv[8] = {p0.x, p0.y, p0.z, p0.w, p1.x, p1.y, p1.z, p1.w};
      float self[8] = {0.f, 0.f, 0.f, 0.f, 0.f, 0.f, 0.f, 0.f};
      h8_acc(*(const float4*)(gj + (size_t)node * HID), self);
      float dnv = dinv[node];
      float4 bb0 = *(const float4*)(bias + j * 8);
      float4 bb1 = *(const float4*)(bias + j * 8 + 4);
      float bbv[8] = {bb0.x, bb0.y, bb0.z, bb0.w, bb1.x, bb1.y, bb1.z, bb1.w};
      float r[8];
#pragma unroll
      for (int k = 0; k < 8; k++) {
        r[k] = dnv * (a0[k] + pv[k] + self[k]) + bbv[k];
        if (do_relu) r[k] = fmaxf(r[k], 0.f);
      }
      *(float4*)(out + (size_t)node * HID + j * 8)     = make_float4(r[0], r[1], r[2], r[3]);
      *(float4*)(out + (size_t)node * HID + j * 8 + 4) = make_float4(r[4], r[5], r[6], r[7]);
    }
  }
}

// ---- fused mean-pool + linear head; batch is SORTED -> contiguous ranges ----
__global__ void pool_head(const float* __restrict__ h, const int* __restrict__ batch,
                          const int* __restrict__ flag, const float* __restrict__ Wl,
                          const float* __restrict__ bl, float* __restrict__ out) {
  __shared__ float acc[8][HID];
  int g = blockIdx.x, t = threadIdx.x;
  int is64 = flag[1];
  int start, end;
  {
    int lo = 0, hi = N_NODES;
    while (lo < hi) { int m = (lo + hi) >> 1; if (load_idx(batch, m, is64) < g) lo = m + 1; else hi = m; }
    start = lo;
    lo = start; hi = N_NODES;
    while (lo < hi) { int m = (lo + hi) >> 1; if (load_idx(batch, m, is64) < g + 1) lo = m + 1; else hi = m; }
    end = lo;
  }
  int c = t & 31, r = t >> 5;
  float s = 0.f;
  for (int i = start + r; i < end; i += 8) s += h[(size_t)i * HID + c];
  acc[r][c] = s;
  __syncthreads();
  if (t < HID) {
    float v = 0.f;
#pragma unroll
    for (int q = 0; q < 8; q++) v += acc[q][t];
    acc[0][t] = v / fmaxf((float)(end - start), 1.0f);
  }
  __syncthreads();
  if (t < OUT_CH) {
    float o = bl[t];
#pragma unroll
    for (int k = 0; k < HID; k++) o += acc[0][k] * Wl[k * OUT_CH + t];
    out[g * OUT_CH + t] = o;
  }
}

extern "C" void kernel_launch(void* const* d_in, const int* in_sizes, int n_in,
                              void* d_out, int out_size, void* d_ws, size_t ws_size,
                              hipStream_t stream) {
  const float* x   = (const float*)d_in[0];
  const int* ei    = (const int*)d_in[1];
  const int* batch = (const int*)d_in[2];
  const float* W1  = (const float*)d_in[3];
  const float* b1  = (const float*)d_in[4];
  const float* W2  = (const float*)d_in[5];
  const float* b2  = (const float*)d_in[6];
  const float* W3  = (const float*)d_in[7];
  const float* b3  = (const float*)d_in[8];
  const float* Wl  = (const float*)d_in[9];
  const float* bl  = (const float*)d_in[10];
  float* out = (float*)d_out;

  char* p = (char*)d_ws;
  auto alloc = [&](size_t bytes) {
    void* r = (void*)p;
    p += (bytes + 255) & ~(size_t)255;
    return r;
  };
  int*    gcur    = (int*)alloc((size_t)NBC * 4);
  int*    bbase   = (int*)alloc((size_t)NBC * 4);
  int*    bstore  = (int*)alloc((size_t)NBC * CAPC * 4);  // 14.4 MB (dead after build_csr)
  int*    csr     = (int*)alloc((size_t)N_EDGES * 4);     // 12.8 MB
  int*    row_ptr = (int*)alloc((size_t)N_NODES * 4);
  int*    deg     = (int*)alloc((size_t)N_NODES * 4);
  int*    deg_lo  = (int*)alloc((size_t)N_NODES * 4);
  float*  dinv    = (float*)alloc((size_t)N_NODES * 4);
  int*    flag    = (int*)alloc(8);
  __half* g       = (__half*)alloc((size_t)N_NODES * HID * 2);  // 6.4 MB fp16
  float*  h       = (float*)alloc((size_t)N_NODES * HID * 4);
  __half* P1      = (__half*)alloc((size_t)4 * 2 * 64 * 8 * 2); // 8 KB
  __half* P2      = (__half*)alloc((size_t)2 * 64 * 8 * 2);     // 2 KB
  __half* P3      = (__half*)alloc((size_t)2 * 64 * 8 * 2);     // 2 KB
  float*  partial = (float*)bstore;   // reuse: live only during agg passes

  detect_i64<<<2, 256, 0, stream>>>(ei, batch, flag);
  pack_w<<<1, 256, 0, stream>>>(W1, W2, W3, P1, P2, P3, gcur);
  bucket_k<<<NRND, BKT, 0, stream>>>(ei, flag, gcur, bstore);
  bscan_k<<<1, 256, 0, stream>>>(gcur, bbase);
  build_csr<<<NBC, 256, 0, stream>>>(bstore, gcur, bbase, csr, row_ptr, deg, deg_lo, dinv);

  const int GB = (N_NODES / 16 + 3) / 4;   // 1563 blocks for gemm
  const int AB = (N_NODES + 31) / 32;      // 3125 blocks for agg (8 nodes/wave)
  gemm_mfma<IN_CH><<<GB, 256, 0, stream>>>(x, P1, dinv, g);
  agg_pull<0><<<AB, 256, 0, stream>>>(g, csr, row_ptr, deg, deg_lo, dinv, b1, partial, h, 0);
  agg_pull<1><<<AB, 256, 0, stream>>>(g, csr, row_ptr, deg, deg_lo, dinv, b1, partial, h, 1);
  gemm_mfma<HID><<<GB, 256, 0, stream>>>(h, P2, dinv, g);
  agg_pull<0><<<AB, 256, 0, stream>>>(g, csr, row_ptr, deg, deg_lo, dinv, b2, partial, h, 0);
  agg_pull<1><<<AB, 256, 0, stream>>>(g, csr, row_ptr, deg, deg_lo, dinv, b2, partial, h, 1);
  gemm_mfma<HID><<<GB, 256, 0, stream>>>(h, P3, dinv, g);
  agg_pull<0><<<AB, 256, 0, stream>>>(g, csr, row_ptr, deg, deg_lo, dinv, b3, partial, h, 0);
  agg_pull<1><<<AB, 256, 0, stream>>>(g, csr, row_ptr, deg, deg_lo, dinv, b3, partial, h, 0);

  pool_head<<<N_GRAPHS, 256, 0, stream>>>(h, batch, flag, Wl, bl, out);
}

// Round 14
// 229.992 us; speedup vs baseline: 1.0507x; 1.0507x over previous
//
#include <hip/hip_runtime.h>
#include <hip/hip_bf16.h>
#include <hip/hip_fp16.h>

#define N_NODES  100000
#define N_GRAPHS 512
#define IN_CH    128
#define HID      32
#define OUT_CH   10
#define N_EDGES  3200000

#define SZC   256                            // nodes per bucket
#define NBC   ((N_NODES + SZC - 1) / SZC)    // 391
#define CAPC  9216                           // mean 8192, +11 sigma
#define SLAB  10240                          // padded per-bucket csr slab (>= CAPC + 3*SZC)
#define RND   8192                           // edges per binning round
#define BKT   1024                           // threads per bucket_k block
#define EPT   8                              // edges per thread per round
#define NRND  ((N_EDGES + RND - 1) / RND)    // 391

typedef _Float16 half8 __attribute__((ext_vector_type(8)));
typedef float    f32x4 __attribute__((ext_vector_type(4)));

// ---- int32/int64 index loader (low word of little-endian int64) ----
__device__ __forceinline__ int load_idx(const int* __restrict__ p, long long pos, int is64) {
  return is64 ? p[2 * pos] : p[(int)pos];
}

// unpack 8 consecutive halfs (loaded as float4) and accumulate into a[8]
__device__ __forceinline__ void h8_acc(float4 raw, float* a) {
  const __half2* ph = (const __half2*)&raw;
#pragma unroll
  for (int q = 0; q < 4; q++) {
    float2 f = __half22float2(ph[q]);
    a[2 * q]     += f.x;
    a[2 * q + 1] += f.y;
  }
}

// Detect whether index buffers are int64. block 0 -> ei flag, block 1 -> batch.
__global__ void detect_i64(const int* __restrict__ ei, const int* __restrict__ batch,
                           int* __restrict__ flag) {
  __shared__ int any_nz;
  const int* buf = (blockIdx.x == 0) ? ei : batch;
  if (threadIdx.x == 0) any_nz = 0;
  __syncthreads();
  for (int i = threadIdx.x; i < 4096; i += 256) {
    if (buf[2 * i + 1] != 0) any_nz = 1;
  }
  __syncthreads();
  if (threadIdx.x == 0) flag[blockIdx.x] = any_nz ? 0 : 1;
}

// ---- pack W[K][32] f32 into MFMA B-fragment order, fp16; also zero gcur ----
__global__ void pack_w(const float* __restrict__ W1, const float* __restrict__ W2,
                       const float* __restrict__ W3, __half* __restrict__ P1,
                       __half* __restrict__ P2, __half* __restrict__ P3,
                       int* __restrict__ gcur) {
  int t = threadIdx.x;
  for (int i = t; i < NBC; i += 256) gcur[i] = 0;
  for (int idx = t; idx < 4 * 2 * 64 * 8; idx += 256) {   // W1: K=128 -> 4 k-steps
    int j = idx & 7, l = (idx >> 3) & 63, ct = (idx >> 9) & 1, s = idx >> 10;
    int k = s * 32 + (l >> 4) * 8 + j, c = ct * 16 + (l & 15);
    P1[idx] = __float2half(W1[k * 32 + c]);
  }
  for (int idx = t; idx < 2 * 64 * 8; idx += 256) {       // W2,W3: K=32 -> 1 k-step
    int j = idx & 7, l = (idx >> 3) & 63, ct = (idx >> 9) & 1;
    int k = (l >> 4) * 8 + j, c = ct * 16 + (l & 15);
    P2[idx] = __float2half(W2[k * 32 + c]);
    P3[idx] = __float2half(W3[k * 32 + c]);
  }
}

// ---- pass 1: round-based binning. 391 blocks x 1024 threads ----
__global__ void bucket_k(const int* __restrict__ ei, const int* __restrict__ flag,
                         int* __restrict__ gcur, int* __restrict__ bstore) {
  __shared__ int hist[NBC];
  __shared__ int base[NBC];
  int is64 = flag[0];
  int t = threadIdx.x;
  int rd = blockIdx.x;
  for (int i = t; i < NBC; i += BKT) hist[i] = 0;
  __syncthreads();
  long long e0 = (long long)rd * RND;
  int   pk[EPT];
  short cb[EPT];
#pragma unroll
  for (int k = 0; k < EPT; k++) {
    long long e = e0 + k * BKT + t;
    if (e < N_EDGES) {
      int s = load_idx(ei, e, is64);
      int d = load_idx(ei, N_EDGES + e, is64);
      pk[k] = (s << 8) | (d & 255);
      cb[k] = (short)(d >> 8);
      atomicAdd(&hist[d >> 8], 1);
    } else {
      cb[k] = -1;
    }
  }
  __syncthreads();
  for (int c = t; c < NBC; c += BKT) {
    int h = hist[c];
    if (h > 0) base[c] = atomicAdd(&gcur[c], h);
  }
  __syncthreads();
#pragma unroll
  for (int k = 0; k < EPT; k++) {
    if (cb[k] >= 0) {
      int c = cb[k];
      int pos = atomicAdd(&base[c], 1);          // LDS cursor from global base
      if (pos < CAPC) bstore[(size_t)c * CAPC + pos] = pk[k];
    }
  }
}

// ---- per-bucket LDS counting sort -> per-node CSR (16B-aligned row starts,
//      fixed per-bucket slab => no global scan kernel needed) + deg + dinv ----
__global__ void build_csr(const int* __restrict__ bstore, const int* __restrict__ gcur,
                          int* __restrict__ csr, int* __restrict__ row_ptr,
                          int* __restrict__ deg, float* __restrict__ dinv) {
  __shared__ int hist[SZC];
  __shared__ int sc[SZC];
  __shared__ int cur[SZC];
  int b = blockIdx.x, t = threadIdx.x;
  hist[t] = 0;
  __syncthreads();
  int cnt = min(gcur[b], CAPC);
  const int* eb = bstore + (size_t)b * CAPC;
  for (int i = t; i < cnt; i += 256) atomicAdd(&hist[eb[i] & 255], 1);
  __syncthreads();
  int own = hist[t];
  int pd  = (own + 3) & ~3;        // pad row to multiple of 4 entries (16B)
  sc[t] = pd;
  __syncthreads();
  for (int off = 1; off < SZC; off <<= 1) {
    int u = (t >= off) ? sc[t - off] : 0;
    __syncthreads();
    sc[t] += u;
    __syncthreads();
  }
  int excl = sc[t] - pd;           // multiple of 4
  int gbase = b * SLAB;            // fixed slab per bucket
  int node = b * SZC + t;
  if (node < N_NODES) {
    row_ptr[node] = gbase + excl;
    deg[node]     = own;
    dinv[node]    = rsqrtf((float)(own + 1));  // +1 self-loop
  }
  cur[t] = excl;
  __syncthreads();
  for (int i = t; i < cnt; i += 256) {
    int pk = eb[i];                              // L2-hot (same block re-read)
    int pos = atomicAdd(&cur[pk & 255], 1);
    csr[gbase + pos] = pk >> 8;
  }
}

// ---- MFMA GEMM: G = fp16( (X @ W) * dinv[row] ), no LDS, no barriers ----
template <int K>
__global__ void gemm_mfma(const float* __restrict__ X, const __half* __restrict__ P,
                          const float* __restrict__ dinv, __half* __restrict__ G) {
  int wid  = threadIdx.x >> 6;
  int lane = threadIdx.x & 63;
  int row0 = (blockIdx.x * 4 + wid) * 16;
  if (row0 >= N_NODES) return;
  int r  = lane & 15;    // A row within tile
  int ko = lane >> 4;    // k-octet selector
  f32x4 acc0 = {0.f, 0.f, 0.f, 0.f};
  f32x4 acc1 = {0.f, 0.f, 0.f, 0.f};
  const float* xrow = X + (size_t)(row0 + r) * K + ko * 8;
#pragma unroll
  for (int s = 0; s < K / 32; s++) {
    float4 xa = *(const float4*)(xrow + s * 32);
    float4 xb = *(const float4*)(xrow + s * 32 + 4);
    half8 a;
    a[0] = (_Float16)xa.x; a[1] = (_Float16)xa.y;
    a[2] = (_Float16)xa.z; a[3] = (_Float16)xa.w;
    a[4] = (_Float16)xb.x; a[5] = (_Float16)xb.y;
    a[6] = (_Float16)xb.z; a[7] = (_Float16)xb.w;
    half8 b0 = *(const half8*)(P + ((size_t)(s * 2 + 0) * 64 + lane) * 8);
    half8 b1 = *(const half8*)(P + ((size_t)(s * 2 + 1) * 64 + lane) * 8);
    acc0 = __builtin_amdgcn_mfma_f32_16x16x32_f16(a, b0, acc0, 0, 0, 0);
    acc1 = __builtin_amdgcn_mfma_f32_16x16x32_f16(a, b1, acc1, 0, 0, 0);
  }
  int col   = lane & 15;
  int rbase = row0 + (lane >> 4) * 4;
#pragma unroll
  for (int i = 0; i < 4; i++) {
    float dn = dinv[rbase + i];
    G[(size_t)(rbase + i) * 32 + col]      = __float2half(acc0[i] * dn);
    G[(size_t)(rbase + i) * 32 + 16 + col] = __float2half(acc1[i] * dn);
  }
}

// ---- pull aggregation: two 4-lane groups per node over CONTIGUOUS halves;
//      row starts 16B-aligned => csr indices load as int4 (4 edges/instr).
//      VMEM per 8 edges: 8 -> 5 instructions. 8 nodes/wave, 12500 waves. ----
__global__ void agg_pull(const __half* __restrict__ g, const int* __restrict__ csr,
                         const int* __restrict__ row_ptr, const int* __restrict__ deg,
                         const float* __restrict__ dinv, const float* __restrict__ bias,
                         float* __restrict__ out, int do_relu) {
  int node = blockIdx.x * 32 + (threadIdx.x >> 3);
  if (node >= N_NODES) return;
  int half = (threadIdx.x >> 2) & 1;   // which contiguous half of the edge list
  int j    = threadIdx.x & 3;          // feature octet: halfs [j*8, j*8+8)
  const __half* gj = g + j * 8;
  int base = row_ptr[node];
  int n    = deg[node];
  int nh   = ((n >> 1) + 3) & ~3;      // half-split point, multiple of 4
  if (nh > n) nh = n;
  int lo = half ? nh : 0;
  int hi = half ? n : nh;
  float a0[8] = {0.f, 0.f, 0.f, 0.f, 0.f, 0.f, 0.f, 0.f};
  float a1[8] = {0.f, 0.f, 0.f, 0.f, 0.f, 0.f, 0.f, 0.f};
  int i = lo;
  for (; i + 3 < hi; i += 4) {         // one int4 index load + 4 row gathers
    int4 s4 = *(const int4*)(csr + base + i);   // 16B-aligned by construction
    float4 r0 = *(const float4*)(gj + (size_t)s4.x * HID);
    float4 r1 = *(const float4*)(gj + (size_t)s4.y * HID);
    float4 r2 = *(const float4*)(gj + (size_t)s4.z * HID);
    float4 r3 = *(const float4*)(gj + (size_t)s4.w * HID);
    h8_acc(r0, a0);
    h8_acc(r1, a1);
    h8_acc(r2, a0);
    h8_acc(r3, a1);
  }
  for (; i < hi; i++) {
    int s0 = csr[base + i];
    h8_acc(*(const float4*)(gj + (size_t)s0 * HID), a0);
  }
#pragma unroll
  for (int k = 0; k < 8; k++) a0[k] += a1[k];
  // combine the two half-streams (lanes differ in bit 2)
#pragma unroll
  for (int k = 0; k < 8; k++) a0[k] += __shfl_xor(a0[k], 4, 64);
  if (half == 0) {
    float self[8] = {0.f, 0.f, 0.f, 0.f, 0.f, 0.f, 0.f, 0.f};
    h8_acc(*(const float4*)(gj + (size_t)node * HID), self);
    float dnv = dinv[node];
    float4 bb0 = *(const float4*)(bias + j * 8);
    float4 bb1 = *(const float4*)(bias + j * 8 + 4);
    float bbv[8] = {bb0.x, bb0.y, bb0.z, bb0.w, bb1.x, bb1.y, bb1.z, bb1.w};
    float r[8];
#pragma unroll
    for (int k = 0; k < 8; k++) {
      r[k] = dnv * (a0[k] + self[k]) + bbv[k];
      if (do_relu) r[k] = fmaxf(r[k], 0.f);
    }
    *(float4*)(out + (size_t)node * HID + j * 8)     = make_float4(r[0], r[1], r[2], r[3]);
    *(float4*)(out + (size_t)node * HID + j * 8 + 4) = make_float4(r[4], r[5], r[6], r[7]);
  }
}

// ---- fused mean-pool + linear head; batch is SORTED -> contiguous ranges ----
__global__ void pool_head(const float* __restrict__ h, const int* __restrict__ batch,
                          const int* __restrict__ flag, const float* __restrict__ Wl,
                          const float* __restrict__ bl, float* __restrict__ out) {
  __shared__ float acc[8][HID];
  int g = blockIdx.x, t = threadIdx.x;
  int is64 = flag[1];
  int start, end;
  {
    int lo = 0, hi = N_NODES;
    while (lo < hi) { int m = (lo + hi) >> 1; if (load_idx(batch, m, is64) < g) lo = m + 1; else hi = m; }
    start = lo;
    lo = start; hi = N_NODES;
    while (lo < hi) { int m = (lo + hi) >> 1; if (load_idx(batch, m, is64) < g + 1) lo = m + 1; else hi = m; }
    end = lo;
  }
  int c = t & 31, r = t >> 5;
  float s = 0.f;
  for (int i = start + r; i < end; i += 8) s += h[(size_t)i * HID + c];
  acc[r][c] = s;
  __syncthreads();
  if (t < HID) {
    float v = 0.f;
#pragma unroll
    for (int q = 0; q < 8; q++) v += acc[q][t];
    acc[0][t] = v / fmaxf((float)(end - start), 1.0f);
  }
  __syncthreads();
  if (t < OUT_CH) {
    float o = bl[t];
#pragma unroll
    for (int k = 0; k < HID; k++) o += acc[0][k] * Wl[k * OUT_CH + t];
    out[g * OUT_CH + t] = o;
  }
}

extern "C" void kernel_launch(void* const* d_in, const int* in_sizes, int n_in,
                              void* d_out, int out_size, void* d_ws, size_t ws_size,
                              hipStream_t stream) {
  const float* x   = (const float*)d_in[0];
  const int* ei    = (const int*)d_in[1];
  const int* batch = (const int*)d_in[2];
  const float* W1  = (const float*)d_in[3];
  const float* b1  = (const float*)d_in[4];
  const float* W2  = (const float*)d_in[5];
  const float* b2  = (const float*)d_in[6];
  const float* W3  = (const float*)d_in[7];
  const float* b3  = (const float*)d_in[8];
  const float* Wl  = (const float*)d_in[9];
  const float* bl  = (const float*)d_in[10];
  float* out = (float*)d_out;

  char* p = (char*)d_ws;
  auto alloc = [&](size_t bytes) {
    void* r = (void*)p;
    p += (bytes + 255) & ~(size_t)255;
    return r;
  };
  int*    gcur    = (int*)alloc((size_t)NBC * 4);
  int*    bstore  = (int*)alloc((size_t)NBC * CAPC * 4);  // 14.4 MB
  int*    csr     = (int*)alloc((size_t)NBC * SLAB * 4);  // 16.0 MB (padded slabs)
  int*    row_ptr = (int*)alloc((size_t)N_NODES * 4);
  int*    deg     = (int*)alloc((size_t)N_NODES * 4);
  float*  dinv    = (float*)alloc((size_t)N_NODES * 4);
  int*    flag    = (int*)alloc(8);
  __half* g       = (__half*)alloc((size_t)N_NODES * HID * 2);  // 6.4 MB fp16
  float*  h       = (float*)alloc((size_t)N_NODES * HID * 4);
  __half* P1      = (__half*)alloc((size_t)4 * 2 * 64 * 8 * 2); // 8 KB
  __half* P2      = (__half*)alloc((size_t)2 * 64 * 8 * 2);     // 2 KB
  __half* P3      = (__half*)alloc((size_t)2 * 64 * 8 * 2);     // 2 KB

  detect_i64<<<2, 256, 0, stream>>>(ei, batch, flag);
  pack_w<<<1, 256, 0, stream>>>(W1, W2, W3, P1, P2, P3, gcur);
  bucket_k<<<NRND, BKT, 0, stream>>>(ei, flag, gcur, bstore);
  build_csr<<<NBC, 256, 0, stream>>>(bstore, gcur, csr, row_ptr, deg, dinv);

  const int GB = (N_NODES / 16 + 3) / 4;   // 1563 blocks for gemm
  const int AB = (N_NODES + 31) / 32;      // 3125 blocks for agg (8 nodes/wave)
  gemm_mfma<IN_CH><<<GB, 256, 0, stream>>>(x, P1, dinv, g);
  agg_pull<<<AB, 256, 0, stream>>>(g, csr, row_ptr, deg, dinv, b1, h, 1);
  gemm_mfma<HID><<<GB, 256, 0, stream>>>(h, P2, dinv, g);
  agg_pull<<<AB, 256, 0, stream>>>(g, csr, row_ptr, deg, dinv, b2, h, 1);
  gemm_mfma<HID><<<GB, 256, 0, stream>>>(h, P3, dinv, g);
  agg_pull<<<AB, 256, 0, stream>>>(g, csr, row_ptr, deg, dinv, b3, h, 0);

  pool_head<<<N_GRAPHS, 256, 0, stream>>>(h, batch, flag, Wl, bl, out);
}

// Round 15
// 225.839 us; speedup vs baseline: 1.0700x; 1.0184x over previous
//
#include <hip/hip_runtime.h>
#include <hip/hip_bf16.h>
#include <hip/hip_fp16.h>

#define N_NODES  100000
#define N_GRAPHS 512
#define IN_CH    128
#define HID      32
#define OUT_CH   10
#define N_EDGES  3200000

#define SZC   256                            // nodes per bucket
#define NBC   ((N_NODES + SZC - 1) / SZC)    // 391
#define CAPC  9216                           // mean 8192, +11 sigma
#define SLAB  10240                          // padded per-bucket csr slab (>= CAPC + 3*SZC)
#define RND   8192                           // edges per binning round
#define BKT   1024                           // threads per bucket_k block
#define EPT   8                              // edges per thread per round
#define NRND  ((N_EDGES + RND - 1) / RND)    // 391

typedef _Float16 half8 __attribute__((ext_vector_type(8)));
typedef float    f32x4 __attribute__((ext_vector_type(4)));

// ---- int32/int64 index loader (low word of little-endian int64) ----
__device__ __forceinline__ int load_idx(const int* __restrict__ p, long long pos, int is64) {
  return is64 ? p[2 * pos] : p[(int)pos];
}

// unpack 8 consecutive halfs (loaded as float4) and accumulate into a[8]
__device__ __forceinline__ void h8_acc(float4 raw, float* a) {
  const __half2* ph = (const __half2*)&raw;
#pragma unroll
  for (int q = 0; q < 4; q++) {
    float2 f = __half22float2(ph[q]);
    a[2 * q]     += f.x;
    a[2 * q + 1] += f.y;
  }
}

// ---- merged setup: blocks 0,1 detect int64-ness of ei/batch; block 2 zeros
//      gcur and packs W1..W3 into MFMA B-fragment order (fp16). ----
__global__ void setup_k(const int* __restrict__ ei, const int* __restrict__ batch,
                        const float* __restrict__ W1, const float* __restrict__ W2,
                        const float* __restrict__ W3, __half* __restrict__ P1,
                        __half* __restrict__ P2, __half* __restrict__ P3,
                        int* __restrict__ flag, int* __restrict__ gcur) {
  __shared__ int any_nz;
  int b = blockIdx.x, t = threadIdx.x;
  if (b < 2) {
    const int* buf = (b == 0) ? ei : batch;
    if (t == 0) any_nz = 0;
    __syncthreads();
    for (int i = t; i < 4096; i += 256) {
      if (buf[2 * i + 1] != 0) any_nz = 1;
    }
    __syncthreads();
    if (t == 0) flag[b] = any_nz ? 0 : 1;
  } else {
    for (int i = t; i < NBC; i += 256) gcur[i] = 0;
    for (int idx = t; idx < 4 * 2 * 64 * 8; idx += 256) {   // W1: K=128 -> 4 k-steps
      int j = idx & 7, l = (idx >> 3) & 63, ct = (idx >> 9) & 1, s = idx >> 10;
      int k = s * 32 + (l >> 4) * 8 + j, c = ct * 16 + (l & 15);
      P1[idx] = __float2half(W1[k * 32 + c]);
    }
    for (int idx = t; idx < 2 * 64 * 8; idx += 256) {       // W2,W3: K=32 -> 1 k-step
      int j = idx & 7, l = (idx >> 3) & 63, ct = (idx >> 9) & 1;
      int k = (l >> 4) * 8 + j, c = ct * 16 + (l & 15);
      P2[idx] = __float2half(W2[k * 32 + c]);
      P3[idx] = __float2half(W3[k * 32 + c]);
    }
  }
}

// ---- pass 1: round-based binning, 391 blocks x 1024 threads.
//      PAIRED edge loads: one int4 (is64) / int2 (is32) = 2 edges per
//      instruction, 16B/8B per lane coalesced -> VMEM instr halved. ----
__global__ void bucket_k(const int* __restrict__ ei, const int* __restrict__ flag,
                         int* __restrict__ gcur, int* __restrict__ bstore) {
  __shared__ int hist[NBC];
  __shared__ int base[NBC];
  int is64 = flag[0];
  int t = threadIdx.x;
  int rd = blockIdx.x;
  for (int i = t; i < NBC; i += BKT) hist[i] = 0;
  __syncthreads();
  long long e0 = (long long)rd * RND;    // even; N_EDGES even => pairs never straddle
  int   pk[EPT];
  short cb[EPT];
#pragma unroll
  for (int k = 0; k < EPT / 2; k++) {
    long long e = e0 + (long long)(k * BKT + t) * 2;  // pair base (even)
    if (e < N_EDGES) {
      int s0, s1, d0, d1;
      if (is64) {
        int4 sv = *(const int4*)(ei + 2 * e);               // src[e], src[e+1]
        int4 dv = *(const int4*)(ei + 2 * (N_EDGES + e));   // dst[e], dst[e+1]
        s0 = sv.x; s1 = sv.z; d0 = dv.x; d1 = dv.z;
      } else {
        int2 sv = *(const int2*)(ei + e);
        int2 dv = *(const int2*)(ei + N_EDGES + e);
        s0 = sv.x; s1 = sv.y; d0 = dv.x; d1 = dv.y;
      }
      pk[2 * k]     = (s0 << 8) | (d0 & 255);
      cb[2 * k]     = (short)(d0 >> 8);
      pk[2 * k + 1] = (s1 << 8) | (d1 & 255);
      cb[2 * k + 1] = (short)(d1 >> 8);
      atomicAdd(&hist[d0 >> 8], 1);
      atomicAdd(&hist[d1 >> 8], 1);
    } else {
      cb[2 * k]     = -1;
      cb[2 * k + 1] = -1;
    }
  }
  __syncthreads();
  for (int c = t; c < NBC; c += BKT) {
    int h = hist[c];
    if (h > 0) base[c] = atomicAdd(&gcur[c], h);
  }
  __syncthreads();
#pragma unroll
  for (int k = 0; k < EPT; k++) {
    if (cb[k] >= 0) {
      int c = cb[k];
      int pos = atomicAdd(&base[c], 1);          // LDS cursor from global base
      if (pos < CAPC) bstore[(size_t)c * CAPC + pos] = pk[k];
    }
  }
}

// ---- per-bucket LDS counting sort -> per-node CSR (16B-aligned row starts,
//      fixed per-bucket slab) + deg + dinv ----
__global__ void build_csr(const int* __restrict__ bstore, const int* __restrict__ gcur,
                          int* __restrict__ csr, int* __restrict__ row_ptr,
                          int* __restrict__ deg, float* __restrict__ dinv) {
  __shared__ int hist[SZC];
  __shared__ int sc[SZC];
  __shared__ int cur[SZC];
  int b = blockIdx.x, t = threadIdx.x;
  hist[t] = 0;
  __syncthreads();
  int cnt = min(gcur[b], CAPC);
  const int* eb = bstore + (size_t)b * CAPC;
  for (int i = t; i < cnt; i += 256) atomicAdd(&hist[eb[i] & 255], 1);
  __syncthreads();
  int own = hist[t];
  int pd  = (own + 3) & ~3;        // pad row to multiple of 4 entries (16B)
  sc[t] = pd;
  __syncthreads();
  for (int off = 1; off < SZC; off <<= 1) {
    int u = (t >= off) ? sc[t - off] : 0;
    __syncthreads();
    sc[t] += u;
    __syncthreads();
  }
  int excl = sc[t] - pd;           // multiple of 4
  int gbase = b * SLAB;            // fixed slab per bucket
  int node = b * SZC + t;
  if (node < N_NODES) {
    row_ptr[node] = gbase + excl;
    deg[node]     = own;
    dinv[node]    = rsqrtf((float)(own + 1));  // +1 self-loop
  }
  cur[t] = excl;
  __syncthreads();
  for (int i = t; i < cnt; i += 256) {
    int pk = eb[i];                              // L2-hot (same block re-read)
    int pos = atomicAdd(&cur[pk & 255], 1);
    csr[gbase + pos] = pk >> 8;
  }
}

// ---- MFMA GEMM: G = fp16( (X @ W) * dinv[row] ), no LDS, no barriers ----
template <int K>
__global__ void gemm_mfma(const float* __restrict__ X, const __half* __restrict__ P,
                          const float* __restrict__ dinv, __half* __restrict__ G) {
  int wid  = threadIdx.x >> 6;
  int lane = threadIdx.x & 63;
  int row0 = (blockIdx.x * 4 + wid) * 16;
  if (row0 >= N_NODES) return;
  int r  = lane & 15;    // A row within tile
  int ko = lane >> 4;    // k-octet selector
  f32x4 acc0 = {0.f, 0.f, 0.f, 0.f};
  f32x4 acc1 = {0.f, 0.f, 0.f, 0.f};
  const float* xrow = X + (size_t)(row0 + r) * K + ko * 8;
#pragma unroll
  for (int s = 0; s < K / 32; s++) {
    float4 xa = *(const float4*)(xrow + s * 32);
    float4 xb = *(const float4*)(xrow + s * 32 + 4);
    half8 a;
    a[0] = (_Float16)xa.x; a[1] = (_Float16)xa.y;
    a[2] = (_Float16)xa.z; a[3] = (_Float16)xa.w;
    a[4] = (_Float16)xb.x; a[5] = (_Float16)xb.y;
    a[6] = (_Float16)xb.z; a[7] = (_Float16)xb.w;
    half8 b0 = *(const half8*)(P + ((size_t)(s * 2 + 0) * 64 + lane) * 8);
    half8 b1 = *(const half8*)(P + ((size_t)(s * 2 + 1) * 64 + lane) * 8);
    acc0 = __builtin_amdgcn_mfma_f32_16x16x32_f16(a, b0, acc0, 0, 0, 0);
    acc1 = __builtin_amdgcn_mfma_f32_16x16x32_f16(a, b1, acc1, 0, 0, 0);
  }
  int col   = lane & 15;
  int rbase = row0 + (lane >> 4) * 4;
#pragma unroll
  for (int i = 0; i < 4; i++) {
    float dn = dinv[rbase + i];
    G[(size_t)(rbase + i) * 32 + col]      = __float2half(acc0[i] * dn);
    G[(size_t)(rbase + i) * 32 + 16 + col] = __float2half(acc1[i] * dn);
  }
}

// ---- pull aggregation: two 4-lane groups per node over contiguous halves;
//      int4 index loads; 8 nodes/wave, 12500 waves.
//      (At the random-request-rate floor: R6/R12/R13 nulls.) ----
__global__ void agg_pull(const __half* __restrict__ g, const int* __restrict__ csr,
                         const int* __restrict__ row_ptr, const int* __restrict__ deg,
                         const float* __restrict__ dinv, const float* __restrict__ bias,
                         float* __restrict__ out, int do_relu) {
  int node = blockIdx.x * 32 + (threadIdx.x >> 3);
  if (node >= N_NODES) return;
  int half = (threadIdx.x >> 2) & 1;   // which contiguous half of the edge list
  int j    = threadIdx.x & 3;          // feature octet: halfs [j*8, j*8+8)
  const __half* gj = g + j * 8;
  int base = row_ptr[node];
  int n    = deg[node];
  int nh   = ((n >> 1) + 3) & ~3;      // half-split point, multiple of 4
  if (nh > n) nh = n;
  int lo = half ? nh : 0;
  int hi = half ? n : nh;
  float a0[8] = {0.f, 0.f, 0.f, 0.f, 0.f, 0.f, 0.f, 0.f};
  float a1[8] = {0.f, 0.f, 0.f, 0.f, 0.f, 0.f, 0.f, 0.f};
  int i = lo;
  for (; i + 3 < hi; i += 4) {         // one int4 index load + 4 row gathers
    int4 s4 = *(const int4*)(csr + base + i);   // 16B-aligned by construction
    float4 r0 = *(const float4*)(gj + (size_t)s4.x * HID);
    float4 r1 = *(const float4*)(gj + (size_t)s4.y * HID);
    float4 r2 = *(const float4*)(gj + (size_t)s4.z * HID);
    float4 r3 = *(const float4*)(gj + (size_t)s4.w * HID);
    h8_acc(r0, a0);
    h8_acc(r1, a1);
    h8_acc(r2, a0);
    h8_acc(r3, a1);
  }
  for (; i < hi; i++) {
    int s0 = csr[base + i];
    h8_acc(*(const float4*)(gj + (size_t)s0 * HID), a0);
  }
#pragma unroll
  for (int k = 0; k < 8; k++) a0[k] += a1[k];
  // combine the two half-streams (lanes differ in bit 2)
#pragma unroll
  for (int k = 0; k < 8; k++) a0[k] += __shfl_xor(a0[k], 4, 64);
  if (half == 0) {
    float self[8] = {0.f, 0.f, 0.f, 0.f, 0.f, 0.f, 0.f, 0.f};
    h8_acc(*(const float4*)(gj + (size_t)node * HID), self);
    float dnv = dinv[node];
    float4 bb0 = *(const float4*)(bias + j * 8);
    float4 bb1 = *(const float4*)(bias + j * 8 + 4);
    float bbv[8] = {bb0.x, bb0.y, bb0.z, bb0.w, bb1.x, bb1.y, bb1.z, bb1.w};
    float r[8];
#pragma unroll
    for (int k = 0; k < 8; k++) {
      r[k] = dnv * (a0[k] + self[k]) + bbv[k];
      if (do_relu) r[k] = fmaxf(r[k], 0.f);
    }
    *(float4*)(out + (size_t)node * HID + j * 8)     = make_float4(r[0], r[1], r[2], r[3]);
    *(float4*)(out + (size_t)node * HID + j * 8 + 4) = make_float4(r[4], r[5], r[6], r[7]);
  }
}

// ---- fused mean-pool + linear head; batch is SORTED -> contiguous ranges ----
__global__ void pool_head(const float* __restrict__ h, const int* __restrict__ batch,
                          const int* __restrict__ flag, const float* __restrict__ Wl,
                          const float* __restrict__ bl, float* __restrict__ out) {
  __shared__ float acc[8][HID];
  int g = blockIdx.x, t = threadIdx.x;
  int is64 = flag[1];
  int start, end;
  {
    int lo = 0, hi = N_NODES;
    while (lo < hi) { int m = (lo + hi) >> 1; if (load_idx(batch, m, is64) < g) lo = m + 1; else hi = m; }
    start = lo;
    lo = start; hi = N_NODES;
    while (lo < hi) { int m = (lo + hi) >> 1; if (load_idx(batch, m, is64) < g + 1) lo = m + 1; else hi = m; }
    end = lo;
  }
  int c = t & 31, r = t >> 5;
  float s = 0.f;
  for (int i = start + r; i < end; i += 8) s += h[(size_t)i * HID + c];
  acc[r][c] = s;
  __syncthreads();
  if (t < HID) {
    float v = 0.f;
#pragma unroll
    for (int q = 0; q < 8; q++) v += acc[q][t];
    acc[0][t] = v / fmaxf((float)(end - start), 1.0f);
  }
  __syncthreads();
  if (t < OUT_CH) {
    float o = bl[t];
#pragma unroll
    for (int k = 0; k < HID; k++) o += acc[0][k] * Wl[k * OUT_CH + t];
    out[g * OUT_CH + t] = o;
  }
}

extern "C" void kernel_launch(void* const* d_in, const int* in_sizes, int n_in,
                              void* d_out, int out_size, void* d_ws, size_t ws_size,
                              hipStream_t stream) {
  const float* x   = (const float*)d_in[0];
  const int* ei    = (const int*)d_in[1];
  const int* batch = (const int*)d_in[2];
  const float* W1  = (const float*)d_in[3];
  const float* b1  = (const float*)d_in[4];
  const float* W2  = (const float*)d_in[5];
  const float* b2  = (const float*)d_in[6];
  const float* W3  = (const float*)d_in[7];
  const float* b3  = (const float*)d_in[8];
  const float* Wl  = (const float*)d_in[9];
  const float* bl  = (const float*)d_in[10];
  float* out = (float*)d_out;

  char* p = (char*)d_ws;
  auto alloc = [&](size_t bytes) {
    void* r = (void*)p;
    p += (bytes + 255) & ~(size_t)255;
    return r;
  };
  int*    gcur    = (int*)alloc((size_t)NBC * 4);
  int*    bstore  = (int*)alloc((size_t)NBC * CAPC * 4);  // 14.4 MB
  int*    csr     = (int*)alloc((size_t)NBC * SLAB * 4);  // 16.0 MB (padded slabs)
  int*    row_ptr = (int*)alloc((size_t)N_NODES * 4);
  int*    deg     = (int*)alloc((size_t)N_NODES * 4);
  float*  dinv    = (float*)alloc((size_t)N_NODES * 4);
  int*    flag    = (int*)alloc(8);
  __half* g       = (__half*)alloc((size_t)N_NODES * HID * 2);  // 6.4 MB fp16
  float*  h       = (float*)alloc((size_t)N_NODES * HID * 4);
  __half* P1      = (__half*)alloc((size_t)4 * 2 * 64 * 8 * 2); // 8 KB
  __half* P2      = (__half*)alloc((size_t)2 * 64 * 8 * 2);     // 2 KB
  __half* P3      = (__half*)alloc((size_t)2 * 64 * 8 * 2);     // 2 KB

  setup_k<<<3, 256, 0, stream>>>(ei, batch, W1, W2, W3, P1, P2, P3, flag, gcur);
  bucket_k<<<NRND, BKT, 0, stream>>>(ei, flag, gcur, bstore);
  build_csr<<<NBC, 256, 0, stream>>>(bstore, gcur, csr, row_ptr, deg, dinv);

  const int GB = (N_NODES / 16 + 3) / 4;   // 1563 blocks for gemm
  const int AB = (N_NODES + 31) / 32;      // 3125 blocks for agg (8 nodes/wave)
  gemm_mfma<IN_CH><<<GB, 256, 0, stream>>>(x, P1, dinv, g);
  agg_pull<<<AB, 256, 0, stream>>>(g, csr, row_ptr, deg, dinv, b1, h, 1);
  gemm_mfma<HID><<<GB, 256, 0, stream>>>(h, P2, dinv, g);
  agg_pull<<<AB, 256, 0, stream>>>(g, csr, row_ptr, deg, dinv, b2, h, 1);
  gemm_mfma<HID><<<GB, 256, 0, stream>>>(h, P3, dinv, g);
  agg_pull<<<AB, 256, 0, stream>>>(g, csr, row_ptr, deg, dinv, b3, h, 0);

  pool_head<<<N_GRAPHS, 256, 0, stream>>>(h, batch, flag, Wl, bl, out);
}

// Round 16
// 211.545 us; speedup vs baseline: 1.1423x; 1.0676x over previous
//
#include <hip/hip_runtime.h>
#include <hip/hip_bf16.h>
#include <hip/hip_fp16.h>

#define N_NODES  100000
#define N_GRAPHS 512
#define IN_CH    128
#define HID      32
#define OUT_CH   10
#define N_EDGES  3200000

#define SZC   256                            // nodes per bucket
#define NBC   ((N_NODES + SZC - 1) / SZC)    // 391
#define CAPC  9216                           // mean 8192, +11 sigma
#define SLAB  10240                          // padded per-bucket csr slab (>= CAPC + 3*SZC)
#define RND   8192                           // edges per binning round
#define BKT   1024                           // threads per bucket_k block
#define EPT   8                              // edges per thread per round
#define NRND  ((N_EDGES + RND - 1) / RND)    // 391

typedef _Float16 half8 __attribute__((ext_vector_type(8)));
typedef float    f32x4 __attribute__((ext_vector_type(4)));

// ---- int32/int64 index loader (low word of little-endian int64) ----
__device__ __forceinline__ int load_idx(const int* __restrict__ p, long long pos, int is64) {
  return is64 ? p[2 * pos] : p[(int)pos];
}

// unpack 8 consecutive halfs (loaded as float4) and accumulate into a[8]
__device__ __forceinline__ void h8_acc(float4 raw, float* a) {
  const __half2* ph = (const __half2*)&raw;
#pragma unroll
  for (int q = 0; q < 4; q++) {
    float2 f = __half22float2(ph[q]);
    a[2 * q]     += f.x;
    a[2 * q + 1] += f.y;
  }
}

// ---- merged setup: blocks 0,1 detect int64-ness of ei/batch; block 2 zeros
//      gcur and packs W1 into MFMA B-fragment order (fp16). W2/W3 are used
//      raw by the fused agg epilogue. ----
__global__ void setup_k(const int* __restrict__ ei, const int* __restrict__ batch,
                        const float* __restrict__ W1, __half* __restrict__ P1,
                        int* __restrict__ flag, int* __restrict__ gcur) {
  __shared__ int any_nz;
  int b = blockIdx.x, t = threadIdx.x;
  if (b < 2) {
    const int* buf = (b == 0) ? ei : batch;
    if (t == 0) any_nz = 0;
    __syncthreads();
    for (int i = t; i < 4096; i += 256) {
      if (buf[2 * i + 1] != 0) any_nz = 1;
    }
    __syncthreads();
    if (t == 0) flag[b] = any_nz ? 0 : 1;
  } else {
    for (int i = t; i < NBC; i += 256) gcur[i] = 0;
    for (int idx = t; idx < 4 * 2 * 64 * 8; idx += 256) {   // W1: K=128 -> 4 k-steps
      int j = idx & 7, l = (idx >> 3) & 63, ct = (idx >> 9) & 1, s = idx >> 10;
      int k = s * 32 + (l >> 4) * 8 + j, c = ct * 16 + (l & 15);
      P1[idx] = __float2half(W1[k * 32 + c]);
    }
  }
}

// ---- pass 1: round-based binning, 391 blocks x 1024 threads, paired loads ----
__global__ void bucket_k(const int* __restrict__ ei, const int* __restrict__ flag,
                         int* __restrict__ gcur, int* __restrict__ bstore) {
  __shared__ int hist[NBC];
  __shared__ int base[NBC];
  int is64 = flag[0];
  int t = threadIdx.x;
  int rd = blockIdx.x;
  for (int i = t; i < NBC; i += BKT) hist[i] = 0;
  __syncthreads();
  long long e0 = (long long)rd * RND;    // even; pairs never straddle
  int   pk[EPT];
  short cb[EPT];
#pragma unroll
  for (int k = 0; k < EPT / 2; k++) {
    long long e = e0 + (long long)(k * BKT + t) * 2;  // pair base (even)
    if (e < N_EDGES) {
      int s0, s1, d0, d1;
      if (is64) {
        int4 sv = *(const int4*)(ei + 2 * e);
        int4 dv = *(const int4*)(ei + 2 * (N_EDGES + e));
        s0 = sv.x; s1 = sv.z; d0 = dv.x; d1 = dv.z;
      } else {
        int2 sv = *(const int2*)(ei + e);
        int2 dv = *(const int2*)(ei + N_EDGES + e);
        s0 = sv.x; s1 = sv.y; d0 = dv.x; d1 = dv.y;
      }
      pk[2 * k]     = (s0 << 8) | (d0 & 255);
      cb[2 * k]     = (short)(d0 >> 8);
      pk[2 * k + 1] = (s1 << 8) | (d1 & 255);
      cb[2 * k + 1] = (short)(d1 >> 8);
      atomicAdd(&hist[d0 >> 8], 1);
      atomicAdd(&hist[d1 >> 8], 1);
    } else {
      cb[2 * k]     = -1;
      cb[2 * k + 1] = -1;
    }
  }
  __syncthreads();
  for (int c = t; c < NBC; c += BKT) {
    int h = hist[c];
    if (h > 0) base[c] = atomicAdd(&gcur[c], h);
  }
  __syncthreads();
#pragma unroll
  for (int k = 0; k < EPT; k++) {
    if (cb[k] >= 0) {
      int c = cb[k];
      int pos = atomicAdd(&base[c], 1);          // LDS cursor from global base
      if (pos < CAPC) bstore[(size_t)c * CAPC + pos] = pk[k];
    }
  }
}

// ---- per-bucket LDS counting sort -> per-node CSR (16B-aligned rows) ----
__global__ void build_csr(const int* __restrict__ bstore, const int* __restrict__ gcur,
                          int* __restrict__ csr, int* __restrict__ row_ptr,
                          int* __restrict__ deg, float* __restrict__ dinv) {
  __shared__ int hist[SZC];
  __shared__ int sc[SZC];
  __shared__ int cur[SZC];
  int b = blockIdx.x, t = threadIdx.x;
  hist[t] = 0;
  __syncthreads();
  int cnt = min(gcur[b], CAPC);
  const int* eb = bstore + (size_t)b * CAPC;
  for (int i = t; i < cnt; i += 256) atomicAdd(&hist[eb[i] & 255], 1);
  __syncthreads();
  int own = hist[t];
  int pd  = (own + 3) & ~3;        // pad row to multiple of 4 entries (16B)
  sc[t] = pd;
  __syncthreads();
  for (int off = 1; off < SZC; off <<= 1) {
    int u = (t >= off) ? sc[t - off] : 0;
    __syncthreads();
    sc[t] += u;
    __syncthreads();
  }
  int excl = sc[t] - pd;           // multiple of 4
  int gbase = b * SLAB;            // fixed slab per bucket
  int node = b * SZC + t;
  if (node < N_NODES) {
    row_ptr[node] = gbase + excl;
    deg[node]     = own;
    dinv[node]    = rsqrtf((float)(own + 1));  // +1 self-loop
  }
  cur[t] = excl;
  __syncthreads();
  for (int i = t; i < cnt; i += 256) {
    int pk = eb[i];                              // L2-hot (same block re-read)
    int pos = atomicAdd(&cur[pk & 255], 1);
    csr[gbase + pos] = pk >> 8;
  }
}

// ---- MFMA GEMM (layer 1 only): G = fp16( (X @ W1) * dinv[row] ) ----
template <int K>
__global__ void gemm_mfma(const float* __restrict__ X, const __half* __restrict__ P,
                          const float* __restrict__ dinv, __half* __restrict__ G) {
  int wid  = threadIdx.x >> 6;
  int lane = threadIdx.x & 63;
  int row0 = (blockIdx.x * 4 + wid) * 16;
  if (row0 >= N_NODES) return;
  int r  = lane & 15;    // A row within tile
  int ko = lane >> 4;    // k-octet selector
  f32x4 acc0 = {0.f, 0.f, 0.f, 0.f};
  f32x4 acc1 = {0.f, 0.f, 0.f, 0.f};
  const float* xrow = X + (size_t)(row0 + r) * K + ko * 8;
#pragma unroll
  for (int s = 0; s < K / 32; s++) {
    float4 xa = *(const float4*)(xrow + s * 32);
    float4 xb = *(const float4*)(xrow + s * 32 + 4);
    half8 a;
    a[0] = (_Float16)xa.x; a[1] = (_Float16)xa.y;
    a[2] = (_Float16)xa.z; a[3] = (_Float16)xa.w;
    a[4] = (_Float16)xb.x; a[5] = (_Float16)xb.y;
    a[6] = (_Float16)xb.z; a[7] = (_Float16)xb.w;
    half8 b0 = *(const half8*)(P + ((size_t)(s * 2 + 0) * 64 + lane) * 8);
    half8 b1 = *(const half8*)(P + ((size_t)(s * 2 + 1) * 64 + lane) * 8);
    acc0 = __builtin_amdgcn_mfma_f32_16x16x32_f16(a, b0, acc0, 0, 0, 0);
    acc1 = __builtin_amdgcn_mfma_f32_16x16x32_f16(a, b1, acc1, 0, 0, 0);
  }
  int col   = lane & 15;
  int rbase = row0 + (lane >> 4) * 4;
#pragma unroll
  for (int i = 0; i < 4; i++) {
    float dn = dinv[rbase + i];
    G[(size_t)(rbase + i) * 32 + col]      = __float2half(acc0[i] * dn);
    G[(size_t)(rbase + i) * 32 + 16 + col] = __float2half(acc1[i] * dn);
  }
}

// ---- pull aggregation (two 4-lane groups per node, contiguous halves,
//      int4 index loads; at the random-request-rate floor).
//      FUSE=1: epilogue computes next layer's g = fp16((relu(h)@Wn)*dinv)
//      via the block's 32x32 h-tile in LDS — deletes the standalone K=32
//      GEMM dispatch and the h global round-trip.
//      FUSE=0: last layer, writes f32 h for pooling. ----
template <int FUSE>
__global__ void agg_pull(const __half* __restrict__ g, const int* __restrict__ csr,
                         const int* __restrict__ row_ptr, const int* __restrict__ deg,
                         const float* __restrict__ dinv, const float* __restrict__ bias,
                         const float* __restrict__ Wn, __half* __restrict__ gout,
                         float* __restrict__ hout, int do_relu) {
  __shared__ float hh[32][33];   // stride-33: (n+k)%32 banks, conflict-free
  __shared__ float Ws[32 * 32];
  int t = threadIdx.x;
  if (FUSE) {
    for (int i = t; i < 1024; i += 256) Ws[i] = Wn[i];
  }
  int node = blockIdx.x * 32 + (t >> 3);   // 3125*32 == N_NODES exactly
  int half = (t >> 2) & 1;
  int j    = t & 3;
  const __half* gj = g + j * 8;
  int base = row_ptr[node];
  int n    = deg[node];
  int nh   = ((n >> 1) + 3) & ~3;
  if (nh > n) nh = n;
  int lo = half ? nh : 0;
  int hi = half ? n : nh;
  float a0[8] = {0.f, 0.f, 0.f, 0.f, 0.f, 0.f, 0.f, 0.f};
  float a1[8] = {0.f, 0.f, 0.f, 0.f, 0.f, 0.f, 0.f, 0.f};
  int i = lo;
  for (; i + 3 < hi; i += 4) {
    int4 s4 = *(const int4*)(csr + base + i);   // 16B-aligned by construction
    float4 r0 = *(const float4*)(gj + (size_t)s4.x * HID);
    float4 r1 = *(const float4*)(gj + (size_t)s4.y * HID);
    float4 r2 = *(const float4*)(gj + (size_t)s4.z * HID);
    float4 r3 = *(const float4*)(gj + (size_t)s4.w * HID);
    h8_acc(r0, a0);
    h8_acc(r1, a1);
    h8_acc(r2, a0);
    h8_acc(r3, a1);
  }
  for (; i < hi; i++) {
    int s0 = csr[base + i];
    h8_acc(*(const float4*)(gj + (size_t)s0 * HID), a0);
  }
#pragma unroll
  for (int k = 0; k < 8; k++) a0[k] += a1[k];
#pragma unroll
  for (int k = 0; k < 8; k++) a0[k] += __shfl_xor(a0[k], 4, 64);
  if (half == 0) {
    float self[8] = {0.f, 0.f, 0.f, 0.f, 0.f, 0.f, 0.f, 0.f};
    h8_acc(*(const float4*)(gj + (size_t)node * HID), self);
    float dnv = dinv[node];
    float4 bb0 = *(const float4*)(bias + j * 8);
    float4 bb1 = *(const float4*)(bias + j * 8 + 4);
    float bbv[8] = {bb0.x, bb0.y, bb0.z, bb0.w, bb1.x, bb1.y, bb1.z, bb1.w};
    float r[8];
#pragma unroll
    for (int k = 0; k < 8; k++) {
      r[k] = dnv * (a0[k] + self[k]) + bbv[k];
      if (do_relu) r[k] = fmaxf(r[k], 0.f);
    }
    if (FUSE) {
      int nl = t >> 3;
#pragma unroll
      for (int k = 0; k < 8; k++) hh[nl][j * 8 + k] = r[k];
    } else {
      *(float4*)(hout + (size_t)node * HID + j * 8)     = make_float4(r[0], r[1], r[2], r[3]);
      *(float4*)(hout + (size_t)node * HID + j * 8 + 4) = make_float4(r[4], r[5], r[6], r[7]);
    }
  }
  if (FUSE) {
    __syncthreads();
    // g_next[node][c] = fp16( (hh[node][:] @ Ws[:,c]) * dinv[node] )
    int nl = t >> 3, cg = t & 7;
    float acc0 = 0.f, acc1 = 0.f, acc2 = 0.f, acc3 = 0.f;
#pragma unroll
    for (int k = 0; k < 32; k++) {
      float hv = hh[nl][k];                        // broadcast within cg-group
      float4 w = *(const float4*)(Ws + k * 32 + cg * 4);
      acc0 += hv * w.x; acc1 += hv * w.y; acc2 += hv * w.z; acc3 += hv * w.w;
    }
    float dn = dinv[node];
    __half2* go = (__half2*)(gout + (size_t)node * 32 + cg * 4);
    go[0] = __halves2half2(__float2half(acc0 * dn), __float2half(acc1 * dn));
    go[1] = __halves2half2(__float2half(acc2 * dn), __float2half(acc3 * dn));
  }
}

// ---- fused mean-pool + linear head; batch is SORTED -> contiguous ranges ----
__global__ void pool_head(const float* __restrict__ h, const int* __restrict__ batch,
                          const int* __restrict__ flag, const float* __restrict__ Wl,
                          const float* __restrict__ bl, float* __restrict__ out) {
  __shared__ float acc[8][HID];
  int g = blockIdx.x, t = threadIdx.x;
  int is64 = flag[1];
  int start, end;
  {
    int lo = 0, hi = N_NODES;
    while (lo < hi) { int m = (lo + hi) >> 1; if (load_idx(batch, m, is64) < g) lo = m + 1; else hi = m; }
    start = lo;
    lo = start; hi = N_NODES;
    while (lo < hi) { int m = (lo + hi) >> 1; if (load_idx(batch, m, is64) < g + 1) lo = m + 1; else hi = m; }
    end = lo;
  }
  int c = t & 31, r = t >> 5;
  float s = 0.f;
  for (int i = start + r; i < end; i += 8) s += h[(size_t)i * HID + c];
  acc[r][c] = s;
  __syncthreads();
  if (t < HID) {
    float v = 0.f;
#pragma unroll
    for (int q = 0; q < 8; q++) v += acc[q][t];
    acc[0][t] = v / fmaxf((float)(end - start), 1.0f);
  }
  __syncthreads();
  if (t < OUT_CH) {
    float o = bl[t];
#pragma unroll
    for (int k = 0; k < HID; k++) o += acc[0][k] * Wl[k * OUT_CH + t];
    out[g * OUT_CH + t] = o;
  }
}

extern "C" void kernel_launch(void* const* d_in, const int* in_sizes, int n_in,
                              void* d_out, int out_size, void* d_ws, size_t ws_size,
                              hipStream_t stream) {
  const float* x   = (const float*)d_in[0];
  const int* ei    = (const int*)d_in[1];
  const int* batch = (const int*)d_in[2];
  const float* W1  = (const float*)d_in[3];
  const float* b1  = (const float*)d_in[4];
  const float* W2  = (const float*)d_in[5];
  const float* b2  = (const float*)d_in[6];
  const float* W3  = (const float*)d_in[7];
  const float* b3  = (const float*)d_in[8];
  const float* Wl  = (const float*)d_in[9];
  const float* bl  = (const float*)d_in[10];
  float* out = (float*)d_out;

  char* p = (char*)d_ws;
  auto alloc = [&](size_t bytes) {
    void* r = (void*)p;
    p += (bytes + 255) & ~(size_t)255;
    return r;
  };
  int*    gcur    = (int*)alloc((size_t)NBC * 4);
  int*    bstore  = (int*)alloc((size_t)NBC * CAPC * 4);  // 14.4 MB
  int*    csr     = (int*)alloc((size_t)NBC * SLAB * 4);  // 16.0 MB (padded slabs)
  int*    row_ptr = (int*)alloc((size_t)N_NODES * 4);
  int*    deg     = (int*)alloc((size_t)N_NODES * 4);
  float*  dinv    = (float*)alloc((size_t)N_NODES * 4);
  int*    flag    = (int*)alloc(8);
  __half* gA      = (__half*)alloc((size_t)N_NODES * HID * 2);  // 6.4 MB fp16
  __half* gB      = (__half*)alloc((size_t)N_NODES * HID * 2);  // 6.4 MB fp16
  float*  h       = (float*)alloc((size_t)N_NODES * HID * 4);
  __half* P1      = (__half*)alloc((size_t)4 * 2 * 64 * 8 * 2); // 8 KB

  setup_k<<<3, 256, 0, stream>>>(ei, batch, W1, P1, flag, gcur);
  bucket_k<<<NRND, BKT, 0, stream>>>(ei, flag, gcur, bstore);
  build_csr<<<NBC, 256, 0, stream>>>(bstore, gcur, csr, row_ptr, deg, dinv);

  const int GB = (N_NODES / 16 + 3) / 4;   // 1563 blocks for gemm1
  const int AB = N_NODES / 32;             // 3125 blocks for agg (exact)
  gemm_mfma<IN_CH><<<GB, 256, 0, stream>>>(x, P1, dinv, gA);
  // layer1 agg + fused gemm2 -> gB
  agg_pull<1><<<AB, 256, 0, stream>>>(gA, csr, row_ptr, deg, dinv, b1, W2, gB, nullptr, 1);
  // layer2 agg + fused gemm3 -> gA
  agg_pull<1><<<AB, 256, 0, stream>>>(gB, csr, row_ptr, deg, dinv, b2, W3, gA, nullptr, 1);
  // layer3 agg -> h (no relu)
  agg_pull<0><<<AB, 256, 0, stream>>>(gA, csr, row_ptr, deg, dinv, b3, nullptr, nullptr, h, 0);

  pool_head<<<N_GRAPHS, 256, 0, stream>>>(h, batch, flag, Wl, bl, out);
}

// Round 17
// 204.349 us; speedup vs baseline: 1.1826x; 1.0352x over previous
//
#include <hip/hip_runtime.h>
#include <hip/hip_bf16.h>
#include <hip/hip_fp16.h>

#define N_NODES  100000
#define N_GRAPHS 512
#define IN_CH    128
#define HID      32
#define OUT_CH   10
#define N_EDGES  3200000

#define SZC   256                            // nodes per bucket
#define NBC   ((N_NODES + SZC - 1) / SZC)    // 391
#define CAPC  9216                           // mean 8192, +11 sigma
#define SLAB  10240                          // padded per-bucket csr slab (>= CAPC + 3*SZC)
#define RND   8192                           // edges per binning round
#define BKT   1024                           // threads per bucket_k block
#define EPT   8                              // edges per thread per round
#define NRND  ((N_EDGES + RND - 1) / RND)    // 391

typedef _Float16 half8 __attribute__((ext_vector_type(8)));
typedef float    f32x4 __attribute__((ext_vector_type(4)));

// ---- int32/int64 index loader (low word of little-endian int64) ----
__device__ __forceinline__ int load_idx(const int* __restrict__ p, long long pos, int is64) {
  return is64 ? p[2 * pos] : p[(int)pos];
}

// unpack 8 consecutive halfs (loaded as float4) and accumulate into a[8]
__device__ __forceinline__ void h8_acc(float4 raw, float* a) {
  const __half2* ph = (const __half2*)&raw;
#pragma unroll
  for (int q = 0; q < 4; q++) {
    float2 f = __half22float2(ph[q]);
    a[2 * q]     += f.x;
    a[2 * q + 1] += f.y;
  }
}

// ---- merged setup: blocks 0,1 detect int64-ness of ei/batch; block 2 zeros
//      gcur + pool and packs W1 into MFMA B-fragment order (fp16). ----
__global__ void setup_k(const int* __restrict__ ei, const int* __restrict__ batch,
                        const float* __restrict__ W1, __half* __restrict__ P1,
                        int* __restrict__ flag, int* __restrict__ gcur,
                        float* __restrict__ pool) {
  __shared__ int any_nz;
  int b = blockIdx.x, t = threadIdx.x;
  if (b < 2) {
    const int* buf = (b == 0) ? ei : batch;
    if (t == 0) any_nz = 0;
    __syncthreads();
    for (int i = t; i < 4096; i += 256) {
      if (buf[2 * i + 1] != 0) any_nz = 1;
    }
    __syncthreads();
    if (t == 0) flag[b] = any_nz ? 0 : 1;
  } else {
    for (int i = t; i < NBC; i += 256) gcur[i] = 0;
    for (int i = t; i < N_GRAPHS * HID; i += 256) pool[i] = 0.f;
    for (int idx = t; idx < 4 * 2 * 64 * 8; idx += 256) {   // W1: K=128 -> 4 k-steps
      int j = idx & 7, l = (idx >> 3) & 63, ct = (idx >> 9) & 1, s = idx >> 10;
      int k = s * 32 + (l >> 4) * 8 + j, c = ct * 16 + (l & 15);
      P1[idx] = __float2half(W1[k * 32 + c]);
    }
  }
}

// ---- pass 1: round-based binning, 391 blocks x 1024 threads, paired loads ----
__global__ void bucket_k(const int* __restrict__ ei, const int* __restrict__ flag,
                         int* __restrict__ gcur, int* __restrict__ bstore) {
  __shared__ int hist[NBC];
  __shared__ int base[NBC];
  int is64 = flag[0];
  int t = threadIdx.x;
  int rd = blockIdx.x;
  for (int i = t; i < NBC; i += BKT) hist[i] = 0;
  __syncthreads();
  long long e0 = (long long)rd * RND;    // even; pairs never straddle
  int   pk[EPT];
  short cb[EPT];
#pragma unroll
  for (int k = 0; k < EPT / 2; k++) {
    long long e = e0 + (long long)(k * BKT + t) * 2;  // pair base (even)
    if (e < N_EDGES) {
      int s0, s1, d0, d1;
      if (is64) {
        int4 sv = *(const int4*)(ei + 2 * e);
        int4 dv = *(const int4*)(ei + 2 * (N_EDGES + e));
        s0 = sv.x; s1 = sv.z; d0 = dv.x; d1 = dv.z;
      } else {
        int2 sv = *(const int2*)(ei + e);
        int2 dv = *(const int2*)(ei + N_EDGES + e);
        s0 = sv.x; s1 = sv.y; d0 = dv.x; d1 = dv.y;
      }
      pk[2 * k]     = (s0 << 8) | (d0 & 255);
      cb[2 * k]     = (short)(d0 >> 8);
      pk[2 * k + 1] = (s1 << 8) | (d1 & 255);
      cb[2 * k + 1] = (short)(d1 >> 8);
      atomicAdd(&hist[d0 >> 8], 1);
      atomicAdd(&hist[d1 >> 8], 1);
    } else {
      cb[2 * k]     = -1;
      cb[2 * k + 1] = -1;
    }
  }
  __syncthreads();
  for (int c = t; c < NBC; c += BKT) {
    int h = hist[c];
    if (h > 0) base[c] = atomicAdd(&gcur[c], h);
  }
  __syncthreads();
#pragma unroll
  for (int k = 0; k < EPT; k++) {
    if (cb[k] >= 0) {
      int c = cb[k];
      int pos = atomicAdd(&base[c], 1);          // LDS cursor from global base
      if (pos < CAPC) bstore[(size_t)c * CAPC + pos] = pk[k];
    }
  }
}

// ---- per-bucket LDS counting sort -> per-node CSR (16B-aligned rows) ----
__global__ void build_csr(const int* __restrict__ bstore, const int* __restrict__ gcur,
                          int* __restrict__ csr, int* __restrict__ row_ptr,
                          int* __restrict__ deg, float* __restrict__ dinv) {
  __shared__ int hist[SZC];
  __shared__ int sc[SZC];
  __shared__ int cur[SZC];
  int b = blockIdx.x, t = threadIdx.x;
  hist[t] = 0;
  __syncthreads();
  int cnt = min(gcur[b], CAPC);
  const int* eb = bstore + (size_t)b * CAPC;
  for (int i = t; i < cnt; i += 256) atomicAdd(&hist[eb[i] & 255], 1);
  __syncthreads();
  int own = hist[t];
  int pd  = (own + 3) & ~3;        // pad row to multiple of 4 entries (16B)
  sc[t] = pd;
  __syncthreads();
  for (int off = 1; off < SZC; off <<= 1) {
    int u = (t >= off) ? sc[t - off] : 0;
    __syncthreads();
    sc[t] += u;
    __syncthreads();
  }
  int excl = sc[t] - pd;           // multiple of 4
  int gbase = b * SLAB;            // fixed slab per bucket
  int node = b * SZC + t;
  if (node < N_NODES) {
    row_ptr[node] = gbase + excl;
    deg[node]     = own;
    dinv[node]    = rsqrtf((float)(own + 1));  // +1 self-loop
  }
  cur[t] = excl;
  __syncthreads();
  for (int i = t; i < cnt; i += 256) {
    int pk = eb[i];                              // L2-hot (same block re-read)
    int pos = atomicAdd(&cur[pk & 255], 1);
    csr[gbase + pos] = pk >> 8;
  }
}

// ---- MFMA GEMM (layer 1 only): G = fp16( (X @ W1) * dinv[row] ) ----
template <int K>
__global__ void gemm_mfma(const float* __restrict__ X, const __half* __restrict__ P,
                          const float* __restrict__ dinv, __half* __restrict__ G) {
  int wid  = threadIdx.x >> 6;
  int lane = threadIdx.x & 63;
  int row0 = (blockIdx.x * 4 + wid) * 16;
  if (row0 >= N_NODES) return;
  int r  = lane & 15;    // A row within tile
  int ko = lane >> 4;    // k-octet selector
  f32x4 acc0 = {0.f, 0.f, 0.f, 0.f};
  f32x4 acc1 = {0.f, 0.f, 0.f, 0.f};
  const float* xrow = X + (size_t)(row0 + r) * K + ko * 8;
#pragma unroll
  for (int s = 0; s < K / 32; s++) {
    float4 xa = *(const float4*)(xrow + s * 32);
    float4 xb = *(const float4*)(xrow + s * 32 + 4);
    half8 a;
    a[0] = (_Float16)xa.x; a[1] = (_Float16)xa.y;
    a[2] = (_Float16)xa.z; a[3] = (_Float16)xa.w;
    a[4] = (_Float16)xb.x; a[5] = (_Float16)xb.y;
    a[6] = (_Float16)xb.z; a[7] = (_Float16)xb.w;
    half8 b0 = *(const half8*)(P + ((size_t)(s * 2 + 0) * 64 + lane) * 8);
    half8 b1 = *(const half8*)(P + ((size_t)(s * 2 + 1) * 64 + lane) * 8);
    acc0 = __builtin_amdgcn_mfma_f32_16x16x32_f16(a, b0, acc0, 0, 0, 0);
    acc1 = __builtin_amdgcn_mfma_f32_16x16x32_f16(a, b1, acc1, 0, 0, 0);
  }
  int col   = lane & 15;
  int rbase = row0 + (lane >> 4) * 4;
#pragma unroll
  for (int i = 0; i < 4; i++) {
    float dn = dinv[rbase + i];
    G[(size_t)(rbase + i) * 32 + col]      = __float2half(acc0[i] * dn);
    G[(size_t)(rbase + i) * 32 + 16 + col] = __float2half(acc1[i] * dn);
  }
}

// ---- pull aggregation (two 4-lane groups per node, contiguous halves,
//      int4 index loads; at the random-request-rate floor).
//      FUSE=1: epilogue computes next layer's g = fp16((relu(h)@Wn)*dinv).
//      FUSE=2: last layer — epilogue accumulates the block's per-graph
//      mean-pool partials (batch sorted => <=2 graph runs per 32-node
//      block => ~37 atomics/block, no contention). ----
template <int FUSE>
__global__ void agg_pull(const __half* __restrict__ g, const int* __restrict__ csr,
                         const int* __restrict__ row_ptr, const int* __restrict__ deg,
                         const float* __restrict__ dinv, const float* __restrict__ bias,
                         const float* __restrict__ Wn, __half* __restrict__ gout,
                         const int* __restrict__ batch, const int* __restrict__ flag,
                         float* __restrict__ pool, int do_relu) {
  __shared__ float hh[32][33];   // stride-33: conflict-free columns
  __shared__ float Ws[32 * 32];
  __shared__ int gids[32];
  int t = threadIdx.x;
  if (FUSE == 1) {
    for (int i = t; i < 1024; i += 256) Ws[i] = Wn[i];
  }
  int node = blockIdx.x * 32 + (t >> 3);   // 3125*32 == N_NODES exactly
  if (FUSE == 2 && t < 32) {
    gids[t] = load_idx(batch, (long long)(blockIdx.x * 32 + t), flag[1]);
  }
  int half = (t >> 2) & 1;
  int j    = t & 3;
  const __half* gj = g + j * 8;
  int base = row_ptr[node];
  int n    = deg[node];
  int nh   = ((n >> 1) + 3) & ~3;
  if (nh > n) nh = n;
  int lo = half ? nh : 0;
  int hi = half ? n : nh;
  float a0[8] = {0.f, 0.f, 0.f, 0.f, 0.f, 0.f, 0.f, 0.f};
  float a1[8] = {0.f, 0.f, 0.f, 0.f, 0.f, 0.f, 0.f, 0.f};
  int i = lo;
  for (; i + 3 < hi; i += 4) {
    int4 s4 = *(const int4*)(csr + base + i);   // 16B-aligned by construction
    float4 r0 = *(const float4*)(gj + (size_t)s4.x * HID);
    float4 r1 = *(const float4*)(gj + (size_t)s4.y * HID);
    float4 r2 = *(const float4*)(gj + (size_t)s4.z * HID);
    float4 r3 = *(const float4*)(gj + (size_t)s4.w * HID);
    h8_acc(r0, a0);
    h8_acc(r1, a1);
    h8_acc(r2, a0);
    h8_acc(r3, a1);
  }
  for (; i < hi; i++) {
    int s0 = csr[base + i];
    h8_acc(*(const float4*)(gj + (size_t)s0 * HID), a0);
  }
#pragma unroll
  for (int k = 0; k < 8; k++) a0[k] += a1[k];
#pragma unroll
  for (int k = 0; k < 8; k++) a0[k] += __shfl_xor(a0[k], 4, 64);
  if (half == 0) {
    float self[8] = {0.f, 0.f, 0.f, 0.f, 0.f, 0.f, 0.f, 0.f};
    h8_acc(*(const float4*)(gj + (size_t)node * HID), self);
    float dnv = dinv[node];
    float4 bb0 = *(const float4*)(bias + j * 8);
    float4 bb1 = *(const float4*)(bias + j * 8 + 4);
    float bbv[8] = {bb0.x, bb0.y, bb0.z, bb0.w, bb1.x, bb1.y, bb1.z, bb1.w};
    int nl = t >> 3;
#pragma unroll
    for (int k = 0; k < 8; k++) {
      float r = dnv * (a0[k] + self[k]) + bbv[k];
      if (do_relu) r = fmaxf(r, 0.f);
      hh[nl][j * 8 + k] = r;
    }
  }
  __syncthreads();
  if (FUSE == 1) {
    // g_next[node][c] = fp16( (hh[node][:] @ Ws[:,c]) * dinv[node] )
    int nl = t >> 3, cg = t & 7;
    float acc0 = 0.f, acc1 = 0.f, acc2 = 0.f, acc3 = 0.f;
#pragma unroll
    for (int k = 0; k < 32; k++) {
      float hv = hh[nl][k];                        // broadcast within cg-group
      float4 w = *(const float4*)(Ws + k * 32 + cg * 4);
      acc0 += hv * w.x; acc1 += hv * w.y; acc2 += hv * w.z; acc3 += hv * w.w;
    }
    float dn = dinv[node];
    __half2* go = (__half2*)(gout + (size_t)node * 32 + cg * 4);
    go[0] = __halves2half2(__float2half(acc0 * dn), __float2half(acc1 * dn));
    go[1] = __halves2half2(__float2half(acc2 * dn), __float2half(acc3 * dn));
  } else {
    // per-graph run-length pool accumulation: thread c (<32) scans 32 rows
    if (t < 32) {
      int cg = gids[0];
      float acc = 0.f;
      for (int nl = 0; nl < 32; nl++) {
        int gid = gids[nl];
        if (gid != cg) {
          atomicAdd(&pool[cg * HID + t], acc);
          acc = 0.f;
          cg = gid;
        }
        acc += hh[nl][t];
      }
      atomicAdd(&pool[cg * HID + t], acc);
    }
  }
}

// ---- head: out[g] = (pool[g]/cnt[g]) @ Wl + bl ; cnt via binary search ----
__global__ void head_k(const float* __restrict__ pool, const int* __restrict__ batch,
                       const int* __restrict__ flag, const float* __restrict__ Wl,
                       const float* __restrict__ bl, float* __restrict__ out) {
  __shared__ float m[HID];
  int g = blockIdx.x, t = threadIdx.x;
  int is64 = flag[1];
  int start, end;
  {
    int lo = 0, hi = N_NODES;
    while (lo < hi) { int mm = (lo + hi) >> 1; if (load_idx(batch, mm, is64) < g) lo = mm + 1; else hi = mm; }
    start = lo;
    lo = start; hi = N_NODES;
    while (lo < hi) { int mm = (lo + hi) >> 1; if (load_idx(batch, mm, is64) < g + 1) lo = mm + 1; else hi = mm; }
    end = lo;
  }
  float inv = 1.0f / fmaxf((float)(end - start), 1.0f);
  if (t < HID) m[t] = pool[g * HID + t] * inv;
  __syncthreads();
  if (t < OUT_CH) {
    float o = bl[t];
#pragma unroll
    for (int k = 0; k < HID; k++) o += m[k] * Wl[k * OUT_CH + t];
    out[g * OUT_CH + t] = o;
  }
}

extern "C" void kernel_launch(void* const* d_in, const int* in_sizes, int n_in,
                              void* d_out, int out_size, void* d_ws, size_t ws_size,
                              hipStream_t stream) {
  const float* x   = (const float*)d_in[0];
  const int* ei    = (const int*)d_in[1];
  const int* batch = (const int*)d_in[2];
  const float* W1  = (const float*)d_in[3];
  const float* b1  = (const float*)d_in[4];
  const float* W2  = (const float*)d_in[5];
  const float* b2  = (const float*)d_in[6];
  const float* W3  = (const float*)d_in[7];
  const float* b3  = (const float*)d_in[8];
  const float* Wl  = (const float*)d_in[9];
  const float* bl  = (const float*)d_in[10];
  float* out = (float*)d_out;

  char* p = (char*)d_ws;
  auto alloc = [&](size_t bytes) {
    void* r = (void*)p;
    p += (bytes + 255) & ~(size_t)255;
    return r;
  };
  int*    gcur    = (int*)alloc((size_t)NBC * 4);
  int*    bstore  = (int*)alloc((size_t)NBC * CAPC * 4);  // 14.4 MB
  int*    csr     = (int*)alloc((size_t)NBC * SLAB * 4);  // 16.0 MB (padded slabs)
  int*    row_ptr = (int*)alloc((size_t)N_NODES * 4);
  int*    deg     = (int*)alloc((size_t)N_NODES * 4);
  float*  dinv    = (float*)alloc((size_t)N_NODES * 4);
  int*    flag    = (int*)alloc(8);
  __half* gA      = (__half*)alloc((size_t)N_NODES * HID * 2);  // 6.4 MB fp16
  __half* gB      = (__half*)alloc((size_t)N_NODES * HID * 2);  // 6.4 MB fp16
  float*  pool    = (float*)alloc((size_t)N_GRAPHS * HID * 4);  // 64 KB
  __half* P1      = (__half*)alloc((size_t)4 * 2 * 64 * 8 * 2); // 8 KB

  setup_k<<<3, 256, 0, stream>>>(ei, batch, W1, P1, flag, gcur, pool);
  bucket_k<<<NRND, BKT, 0, stream>>>(ei, flag, gcur, bstore);
  build_csr<<<NBC, 256, 0, stream>>>(bstore, gcur, csr, row_ptr, deg, dinv);

  const int GB = (N_NODES / 16 + 3) / 4;   // 1563 blocks for gemm1
  const int AB = N_NODES / 32;             // 3125 blocks for agg (exact)
  gemm_mfma<IN_CH><<<GB, 256, 0, stream>>>(x, P1, dinv, gA);
  // layer1 agg + fused gemm2 -> gB
  agg_pull<1><<<AB, 256, 0, stream>>>(gA, csr, row_ptr, deg, dinv, b1, W2, gB,
                                      nullptr, nullptr, nullptr, 1);
  // layer2 agg + fused gemm3 -> gA
  agg_pull<1><<<AB, 256, 0, stream>>>(gB, csr, row_ptr, deg, dinv, b2, W3, gA,
                                      nullptr, nullptr, nullptr, 1);
  // layer3 agg + fused mean-pool partials (no relu)
  agg_pull<2><<<AB, 256, 0, stream>>>(gA, csr, row_ptr, deg, dinv, b3, nullptr, nullptr,
                                      batch, flag, pool, 0);

  head_k<<<N_GRAPHS, 64, 0, stream>>>(pool, batch, flag, Wl, bl, out);
}